// Round 8
// baseline (223.909 us; speedup 1.0000x reference)
//
#include <hip/hip_runtime.h>

// CompressedLinear: out = x[8192,4096] @ (W_int8[4096,4096]*scale)^T + bias.
// Round 8: int8 8-phase pipeline at 128x128 tile -> LDS 64 KiB -> 2 blocks/CU
// (round 7 was 128 KiB = 1 block/CU, so barrier-lockstep phases had no other
// block to hide behind; MfmaUtil stuck at 41.5%). 4 waves (2M x 2N), BKB=128
// int8: rows stay 128 B / granules 16 B, so the verified two-level swizzle
// (zero conflicts in rounds 6-7) is unchanged.
//
// Stage ledger (iter computes t->buf0, t+1->buf1; stage group = 4 gloads):
//   g0: ldA0,ldB0 | g1: ldB1 | g2: ldA1 + stageB0<-(t+2)   [B dead after g1]
//   g3: stageA0<-(t+2) + WAITV8                            [A dead after g2]
//   g4..g7 mirror on buf1, staging t+3; WAITV8 at g7.
// Queue at g3-wait: [B1,A1(t+1)=8][B0,A0(t+2)=8] -> leaves 8 -> buf1 landed.
// Queue at g7-wait: [B0,A0(t+2)=8][B1,A1(t+3)=8] -> leaves 8 -> buf0 landed.
// Prologue stages B0,A0(t0),B1,A1(t1) + WAITV8. Tail peeled with WAITV0 at
// its g3 (no stages exist to keep the count).

#define BM 128
#define BN 128
#define BKB 128                 // K-bytes per tile = 128 int8

constexpr int Mdim = 8192;
constexpr int Ndim = 4096;
constexpr int Kdim = 4096;
constexpr int KT = Kdim / BKB;  // 32

typedef __attribute__((ext_vector_type(4)))  int   int32x4;
typedef __attribute__((ext_vector_type(16))) int   int32x16;
typedef __attribute__((ext_vector_type(8)))  short short8;
typedef __attribute__((ext_vector_type(4)))  float f32x4;
typedef unsigned short ushort_t;

__device__ __forceinline__ unsigned short f2bf(float f) {
    union { float f; unsigned u; } v; v.f = f;
    unsigned r = v.u + 0x7FFFu + ((v.u >> 16) & 1u);
    return (unsigned short)(r >> 16);
}

__device__ __forceinline__ void gload_lds16(const void* g, void* l) {
    __builtin_amdgcn_global_load_lds(
        (const __attribute__((address_space(1))) void*)g,
        (__attribute__((address_space(3))) void*)l, 16, 0, 0);
}

#define BARRIER() __builtin_amdgcn_s_barrier()
#define LGKM0()   asm volatile("s_waitcnt lgkmcnt(0)" ::: "memory")
#define WAITV0()  asm volatile("s_waitcnt vmcnt(0)" ::: "memory")
#define WAITV8()  asm volatile("s_waitcnt vmcnt(8)" ::: "memory")

// one phase cluster: 1 m-tile x 1 n-tile x 4 k-steps = 4 MFMA (i8 32x32x32)
#define MFMAQ(MT, NT) do {                                                   \
    __builtin_amdgcn_s_setprio(1);                                           \
    _Pragma("unroll") for (int ks = 0; ks < 4; ++ks)                         \
        acc[MT][NT] = __builtin_amdgcn_mfma_i32_32x32x32_i8(                 \
            af[MT][ks], bf[NT][ks], acc[MT][NT], 0, 0, 0);                   \
    __builtin_amdgcn_s_setprio(0);                                           \
} while (0)

// ---------------- prep kernels ----------------------------------------------

// per-row symmetric int8 quantization of x; one block per row
__global__ __launch_bounds__(256)
void quant_x_rowwise(const float* __restrict__ x, char* __restrict__ xq,
                     float* __restrict__ sx) {
    const int row = blockIdx.x;
    const float4* xr = reinterpret_cast<const float4*>(x + (size_t)row * Kdim);
    const int tid = threadIdx.x;
    float4 v[4];
    float am = 0.f;
    #pragma unroll
    for (int j = 0; j < 4; ++j) {
        v[j] = xr[tid + 256 * j];
        am = fmaxf(am, fmaxf(fmaxf(fabsf(v[j].x), fabsf(v[j].y)),
                             fmaxf(fabsf(v[j].z), fabsf(v[j].w))));
    }
    #pragma unroll
    for (int off = 32; off; off >>= 1)
        am = fmaxf(am, __shfl_xor(am, off, 64));
    __shared__ float red[4];
    if ((tid & 63) == 0) red[tid >> 6] = am;
    __syncthreads();
    am = fmaxf(fmaxf(red[0], red[1]), fmaxf(red[2], red[3]));
    am = fmaxf(am, 1e-30f);
    if (tid == 0) sx[row] = am / 127.f;
    const float inv = 127.f / am;
    int* outw = reinterpret_cast<int*>(xq + (size_t)row * Kdim);
    #pragma unroll
    for (int j = 0; j < 4; ++j) {
        const int q0 = (int)rintf(v[j].x * inv) & 255;
        const int q1 = (int)rintf(v[j].y * inv) & 255;
        const int q2 = (int)rintf(v[j].z * inv) & 255;
        const int q3 = (int)rintf(v[j].w * inv) & 255;
        outw[tid + 256 * j] = q0 | (q1 << 8) | (q2 << 16) | (q3 << 24);
    }
}

// pack W int32 (values in [-128,127]) -> int8
__global__ __launch_bounds__(256)
void pack_w_int8(const int* __restrict__ w, char* __restrict__ wq, int n4) {
    int idx = blockIdx.x * blockDim.x + threadIdx.x;
    const int stride = gridDim.x * blockDim.x;
    int* out = reinterpret_cast<int*>(wq);
    for (int i = idx; i < n4; i += stride) {
        const int4 a = reinterpret_cast<const int4*>(w)[i];
        out[i] = (a.x & 255) | ((a.y & 255) << 8) |
                 ((a.z & 255) << 16) | ((a.w & 255) << 24);
    }
}

// ---------------- 128x128 8-phase int8 GEMM (2 blocks/CU) -------------------

__global__ __launch_bounds__(256, 2)
void gemm_i8_128(const char* __restrict__ A,   // [M][K] int8
                 const char* __restrict__ B,   // [N][K] int8
                 const float* __restrict__ scale,
                 const float* __restrict__ bias,
                 const float* __restrict__ sx,
                 float* __restrict__ Out)
{
    // [buf][A,B][128 rows x 128 B] = 64 KiB
    __shared__ __align__(16) char smem[2][2][16384];

    const int tid = threadIdx.x;
    int bid = blockIdx.x;
    bid = (bid & 7) * 256 + (bid >> 3);         // bijective XCD swizzle (2048%8==0)
    const int tn = bid & 31;                    // N/BN = 32
    const int tm = bid >> 5;                    // M/BM = 64
    const int brow = tm * BM;
    const int bcol = tn * BN;

    const int lane = tid & 63;
    const int w    = tid >> 6;                  // 4 waves
    const int wr   = w >> 1;                    // 2 M-waves
    const int wc   = w & 1;                     // 2 N-waves
    const int r32  = lane & 31;
    const int h    = lane >> 5;                 // k-group
    const size_t K1 = (size_t)Kdim;             // row stride in bytes (int8)

    // staging: rows w*8 + (lane>>3) + 32*i, i=0..3 -> covers 0..127.
    // two-level swizzle nibble = (l&7) ^ (row&7) ^ ((row>>3)&3)
    //                          = (l&7) ^ (lane>>3) ^ (w&3)   [w<4, +32 rows ≡ 0 mod 4]
    const int swzb = ((lane & 7) ^ (lane >> 3) ^ (w & 3)) << 4;
    const char* aStageSrc = A + (size_t)(brow + w * 8 + (lane >> 3)) * K1 + swzb;
    const char* bStageSrc = B + (size_t)(bcol + w * 8 + (lane >> 3)) * K1 + swzb;

    auto stageA = [&](int bufb, int tt) {       // 4 gloads = 1 stage group
        const char* s = aStageSrc + (size_t)tt * BKB;
        char* d = &smem[bufb][0][w * 1024];
        #pragma unroll
        for (int i = 0; i < 4; ++i)
            gload_lds16(s + (size_t)(32 * i) * K1, d + i * 4096);
    };
    auto stageB = [&](int bufb, int tt) {
        const char* s = bStageSrc + (size_t)tt * BKB;
        char* d = &smem[bufb][1][w * 1024];
        #pragma unroll
        for (int i = 0; i < 4; ++i)
            gload_lds16(s + (size_t)(32 * i) * K1, d + i * 4096);
    };

    // ds_read bases (identical geometry to rounds 6/7: 128B rows)
    const char* aBase[2] = { &smem[0][0][0] + (wr * 64 + r32) * 128,
                             &smem[1][0][0] + (wr * 64 + r32) * 128 };
    const char* bBase[2] = { &smem[0][1][0] + (wc * 64 + r32) * 128,
                             &smem[1][1][0] + (wc * 64 + r32) * 128 };
    const int frx = ((r32 & 7) ^ (r32 >> 3)) << 4;
    int colb[4];
    #pragma unroll
    for (int ks = 0; ks < 4; ++ks) colb[ks] = (ks * 32 + h * 16) ^ frx;

    int32x16 acc[2][2] = {};     // [m-tile][n-tile]
    int32x4 af[2][4], bf[2][4];  // [tile][k-step], 16 int8 each

    auto ldA = [&](const char* base, int mt) {
        #pragma unroll
        for (int ks = 0; ks < 4; ++ks)
            af[mt][ks] = *reinterpret_cast<const int32x4*>(base + mt * 4096 + colb[ks]);
    };
    auto ldB = [&](const char* base, int nt) {
        #pragma unroll
        for (int ks = 0; ks < 4; ++ks)
            bf[nt][ks] = *reinterpret_cast<const int32x4*>(base + nt * 4096 + colb[ks]);
    };

    // ---- prologue: buf0<-t0, buf1<-t1; first 8 ops (buf0) landed
    stageB(0, 0); stageA(0, 0);
    stageB(1, 1); stageA(1, 1);
    WAITV8();
    BARRIER();

    // ---- main loop: 15 iterations, all stages unconditional ----
    for (int i = 0; i < KT / 2 - 1; ++i) {
        const int t = 2 * i;

        // g0
        ldA(aBase[0], 0); ldB(bBase[0], 0);
        BARRIER(); LGKM0();
        MFMAQ(0, 0);
        BARRIER();
        // g1
        ldB(bBase[0], 1);
        BARRIER(); LGKM0();
        MFMAQ(0, 1);
        BARRIER();
        // g2  (buf0.B dead after g1 -> stage t+2)
        ldA(aBase[0], 1);
        stageB(0, t + 2);
        BARRIER(); LGKM0();
        MFMAQ(1, 0);
        BARRIER();
        // g3  (buf0.A dead after g2 -> stage t+2; wait: buf1/t+1 landed)
        stageA(0, t + 2);
        BARRIER(); LGKM0();
        MFMAQ(1, 1);
        WAITV8();
        BARRIER();
        // g4
        ldA(aBase[1], 0); ldB(bBase[1], 0);
        BARRIER(); LGKM0();
        MFMAQ(0, 0);
        BARRIER();
        // g5
        ldB(bBase[1], 1);
        BARRIER(); LGKM0();
        MFMAQ(0, 1);
        BARRIER();
        // g6
        ldA(aBase[1], 1);
        stageB(1, t + 3);
        BARRIER(); LGKM0();
        MFMAQ(1, 0);
        BARRIER();
        // g7  (wait: buf0/t+2 landed)
        stageA(1, t + 3);
        BARRIER(); LGKM0();
        MFMAQ(1, 1);
        WAITV8();
        BARRIER();
    }

    // ---- peeled tail: t = KT-2; buf1 holds t+1 = KT-1 (<=8 ops in flight).
    {
        // g0
        ldA(aBase[0], 0); ldB(bBase[0], 0);
        BARRIER(); LGKM0();
        MFMAQ(0, 0);
        BARRIER();
        // g1
        ldB(bBase[0], 1);
        BARRIER(); LGKM0();
        MFMAQ(0, 1);
        BARRIER();
        // g2
        ldA(aBase[0], 1);
        BARRIER(); LGKM0();
        MFMAQ(1, 0);
        BARRIER();
        // g3: drain everything -> buf1 guaranteed landed
        MFMAQ(1, 1);
        WAITV0();
        BARRIER();
        // g4..g7: no LDS writes remain, data deps order reads vs MFMA
        ldA(aBase[1], 0); ldB(bBase[1], 0);
        LGKM0();
        MFMAQ(0, 0);
        ldB(bBase[1], 1);
        LGKM0();
        MFMAQ(0, 1);
        ldA(aBase[1], 1);
        LGKM0();
        MFMAQ(1, 0);
        MFMAQ(1, 1);
    }

    // epilogue: out = acc * scale[col] * scale_x[row] + bias[col]
    // C/D (32x32): col=lane&31, row=(reg&3)+8*(reg>>2)+4*(lane>>5)
    #pragma unroll
    for (int nt = 0; nt < 2; ++nt) {
        const int col = bcol + wc * 64 + nt * 32 + r32;
        const float sc = scale[col];
        const float bi = bias[col];
        #pragma unroll
        for (int mt = 0; mt < 2; ++mt) {
            const int rb = brow + wr * 64 + mt * 32 + 4 * h;
            #pragma unroll
            for (int q = 0; q < 4; ++q) {
                const int r4 = rb + 8 * q;
                #pragma unroll
                for (int r = 0; r < 4; ++r) {
                    const float sxr = sx[r4 + r];
                    Out[(size_t)(r4 + r) * Ndim + col] =
                        (float)acc[mt][nt][q * 4 + r] * (sc * sxr) + bi;
                }
            }
        }
    }
}

// ---------------- fallback (round-1 kernel) if ws too small -----------------

__device__ __forceinline__ int swz_fb(int row, int colbyte) {
    return row * 128 + (colbyte ^ ((row & 7) << 4));
}

__global__ __launch_bounds__(256)
void compressed_linear_fb(const float* __restrict__ X,
                          const int*   __restrict__ W,
                          const float* __restrict__ scale,
                          const float* __restrict__ bias,
                          float* __restrict__ Out)
{
    __shared__ __align__(16) ushort_t lA[128 * 64];
    __shared__ __align__(16) ushort_t lB[128 * 64];
    const int tid = threadIdx.x;
    const int bid = blockIdx.x;
    const int tn = bid & 31, tm = bid >> 5;
    const int brow = tm * 128, bcol = tn * 128;
    const int r0 = tid >> 3, c0 = tid & 7;
    float4 aPre[4][2]; int4 bPre[4][2];
    const int lane = tid & 63, w = tid >> 6;
    const int wr = w >> 1, wc = w & 1, fr = lane & 15, fq = lane >> 4;
    f32x4 acc[4][4] = {};

    auto loadTiles = [&](int t) {
        const int k0 = t * 64;
        #pragma unroll
        for (int i = 0; i < 4; i++) {
            const int row = r0 + 32 * i;
            const float4* pa = reinterpret_cast<const float4*>(X + (size_t)(brow + row) * Kdim + k0 + c0 * 8);
            aPre[i][0] = pa[0]; aPre[i][1] = pa[1];
            const int4* pb = reinterpret_cast<const int4*>(W + (size_t)(bcol + row) * Kdim + k0 + c0 * 8);
            bPre[i][0] = pb[0]; bPre[i][1] = pb[1];
        }
    };
    auto writeLDS = [&]() {
        #pragma unroll
        for (int i = 0; i < 4; i++) {
            const int row = r0 + 32 * i;
            const int off = swz_fb(row, c0 * 16);
            short8 va, vb;
            va[0] = (short)f2bf(aPre[i][0].x); va[1] = (short)f2bf(aPre[i][0].y);
            va[2] = (short)f2bf(aPre[i][0].z); va[3] = (short)f2bf(aPre[i][0].w);
            va[4] = (short)f2bf(aPre[i][1].x); va[5] = (short)f2bf(aPre[i][1].y);
            va[6] = (short)f2bf(aPre[i][1].z); va[7] = (short)f2bf(aPre[i][1].w);
            vb[0] = (short)f2bf((float)bPre[i][0].x); vb[1] = (short)f2bf((float)bPre[i][0].y);
            vb[2] = (short)f2bf((float)bPre[i][0].z); vb[3] = (short)f2bf((float)bPre[i][0].w);
            vb[4] = (short)f2bf((float)bPre[i][1].x); vb[5] = (short)f2bf((float)bPre[i][1].y);
            vb[6] = (short)f2bf((float)bPre[i][1].z); vb[7] = (short)f2bf((float)bPre[i][1].w);
            *reinterpret_cast<short8*>(reinterpret_cast<char*>(lA) + off) = va;
            *reinterpret_cast<short8*>(reinterpret_cast<char*>(lB) + off) = vb;
        }
    };

    loadTiles(0);
    for (int t = 0; t < Kdim / 64; t++) {
        writeLDS();
        __syncthreads();
        if (t + 1 < Kdim / 64) loadTiles(t + 1);
        #pragma unroll
        for (int kk = 0; kk < 2; kk++) {
            short8 afv[4], bfv[4];
            const int cb = kk * 64 + fq * 16;
            #pragma unroll
            for (int m = 0; m < 4; m++) {
                const int row = wr * 64 + m * 16 + fr;
                afv[m] = *reinterpret_cast<const short8*>(reinterpret_cast<const char*>(lA) + swz_fb(row, cb));
            }
            #pragma unroll
            for (int n = 0; n < 4; n++) {
                const int row = wc * 64 + n * 16 + fr;
                bfv[n] = *reinterpret_cast<const short8*>(reinterpret_cast<const char*>(lB) + swz_fb(row, cb));
            }
            #pragma unroll
            for (int m = 0; m < 4; m++)
                #pragma unroll
                for (int n = 0; n < 4; n++)
                    acc[m][n] = __builtin_amdgcn_mfma_f32_16x16x32_bf16(afv[m], bfv[n], acc[m][n], 0, 0, 0);
        }
        __syncthreads();
    }
    #pragma unroll
    for (int n = 0; n < 4; n++) {
        const int col = bcol + wc * 64 + n * 16 + fr;
        const float sc = scale[col];
        const float bi = bias[col];
        #pragma unroll
        for (int m = 0; m < 4; m++) {
            const int rbase = brow + wr * 64 + m * 16 + fq * 4;
            #pragma unroll
            for (int j = 0; j < 4; j++)
                Out[(size_t)(rbase + j) * Ndim + col] = acc[m][n][j] * sc + bi;
        }
    }
}

// ---------------------------------------------------------------------------

extern "C" void kernel_launch(void* const* d_in, const int* in_sizes, int n_in,
                              void* d_out, int out_size, void* d_ws, size_t ws_size,
                              hipStream_t stream) {
    const float* x     = (const float*)d_in[0];
    const int*   w8    = (const int*)d_in[1];
    const float* scale = (const float*)d_in[2];
    const float* bias  = (const float*)d_in[3];
    float* out = (float*)d_out;

    const size_t xq_bytes = (size_t)Mdim * Kdim;        // 32 MiB
    const size_t wq_bytes = (size_t)Ndim * Kdim;        // 16 MiB
    const size_t sx_bytes = (size_t)Mdim * sizeof(float);

    if (ws_size >= xq_bytes + wq_bytes + sx_bytes) {
        char*  xq = (char*)d_ws;
        char*  wq = (char*)d_ws + xq_bytes;
        float* sx = (float*)((char*)d_ws + xq_bytes + wq_bytes);
        quant_x_rowwise<<<Mdim, 256, 0, stream>>>(x, xq, sx);
        pack_w_int8<<<2048, 256, 0, stream>>>(w8, wq, (Ndim * Kdim) / 4);
        dim3 grid((Mdim / BM) * (Ndim / BN));           // 64*32 = 2048 blocks
        gemm_i8_128<<<grid, dim3(256), 0, stream>>>(xq, wq, scale, bias, sx, out);
    } else {
        dim3 grid((Mdim / 128) * (Ndim / 128));         // 2048 blocks
        compressed_linear_fb<<<grid, dim3(256), 0, stream>>>(x, w8, scale, bias, out);
    }
}

// Round 9
// 194.511 us; speedup vs baseline: 1.1511x; 1.1511x over previous
//
#include <hip/hip_runtime.h>

// CompressedLinear: out = x[8192,4096] @ (W_int8[4096,4096]*scale)^T + bias.
// Round 9: revert to round-7 geometry (256x256, 8 waves, int8, BKB=128 —
// 147us, locality proven), replace the 4-phase/K-tile barrier lattice
// (8 barriers/K-tile -> LDS and MFMA serialized, 2330+2800 cyc summed) with a
// merged 2-barrier/K-tile segment so the pipes overlap:
//   pre-BAR: ldB(8) + ldA-h0(8)   [reads of this tile]
//   BAR; C0 (16 MFMA, mt0-1)  ||  ldA-h1(8, af reused)  ||  8 stage gloads
//   C1 (16 MFMA, mt2-3); WAITV4; BAR
// No explicit lgkmcnt: plain-C++ ds_reads get compiler partial waits, so
// A1-latency hides under C0.
//
// Stage ledger (segment s = tile s, buf c = s&1; groups of 4 gloads):
//   seg s stages: A(buf 1-c <- s+1) THEN B(buf c <- s+2).
//   - A(1-c): old content (tile s-1) read-issued seg s-1; >=1 barrier before
//     this stage-issue (end-of-s-1 BAR).  B(c): read pre-BAR this seg. Both
//     respect "barrier between read-issue and stage-issue" (round-3 lesson).
//   - end-of-seg wait: in-flight = [B(1-c,s+1)][A(1-c,s+1)][B(c,s+2)] = 12
//     -> WAITV4 leaves newest B only => buf(s+1) fully landed.  Prologue:
//     A+B(buf0,t0) + B(buf1,t1) = 12, WAITV4. Tail: seg KT-2 stages only
//     A(buf1,KT-1), WAITV0 drains; seg KT-1 stages nothing.

#define BM 256
#define BN 256
#define BKB 128                 // K-bytes per tile = 128 int8

constexpr int Mdim = 8192;
constexpr int Ndim = 4096;
constexpr int Kdim = 4096;
constexpr int KT = Kdim / BKB;  // 32

typedef __attribute__((ext_vector_type(4)))  int   int32x4;
typedef __attribute__((ext_vector_type(16))) int   int32x16;
typedef __attribute__((ext_vector_type(8)))  short short8;
typedef __attribute__((ext_vector_type(4)))  float f32x4;
typedef unsigned short ushort_t;

__device__ __forceinline__ unsigned short f2bf(float f) {
    union { float f; unsigned u; } v; v.f = f;
    unsigned r = v.u + 0x7FFFu + ((v.u >> 16) & 1u);
    return (unsigned short)(r >> 16);
}

__device__ __forceinline__ void gload_lds16(const void* g, void* l) {
    __builtin_amdgcn_global_load_lds(
        (const __attribute__((address_space(1))) void*)g,
        (__attribute__((address_space(3))) void*)l, 16, 0, 0);
}

#define BARRIER() __builtin_amdgcn_s_barrier()
#define WAITV0()  asm volatile("s_waitcnt vmcnt(0)" ::: "memory")
#define WAITV4()  asm volatile("s_waitcnt vmcnt(4)" ::: "memory")

// cluster: 2 m-tiles x 2 n-tiles x 4 k-steps = 16 MFMA (i8 32x32x32).
// af[0..1] holds the current m-pair's fragments (reused across clusters).
#define CLUSTER(MBASE) do {                                                  \
    __builtin_amdgcn_s_setprio(1);                                           \
    _Pragma("unroll") for (int mt = 0; mt < 2; ++mt)                         \
    _Pragma("unroll") for (int nt = 0; nt < 2; ++nt)                         \
    _Pragma("unroll") for (int ks = 0; ks < 4; ++ks)                         \
        acc[(MBASE)+mt][nt] = __builtin_amdgcn_mfma_i32_32x32x32_i8(         \
            af[mt][ks], bf[nt][ks], acc[(MBASE)+mt][nt], 0, 0, 0);           \
    __builtin_amdgcn_s_setprio(0);                                           \
} while (0)

// ---------------- prep kernels ----------------------------------------------

// per-row symmetric int8 quantization of x; one block per row
__global__ __launch_bounds__(256)
void quant_x_rowwise(const float* __restrict__ x, char* __restrict__ xq,
                     float* __restrict__ sx) {
    const int row = blockIdx.x;
    const float4* xr = reinterpret_cast<const float4*>(x + (size_t)row * Kdim);
    const int tid = threadIdx.x;
    float4 v[4];
    float am = 0.f;
    #pragma unroll
    for (int j = 0; j < 4; ++j) {
        v[j] = xr[tid + 256 * j];
        am = fmaxf(am, fmaxf(fmaxf(fabsf(v[j].x), fabsf(v[j].y)),
                             fmaxf(fabsf(v[j].z), fabsf(v[j].w))));
    }
    #pragma unroll
    for (int off = 32; off; off >>= 1)
        am = fmaxf(am, __shfl_xor(am, off, 64));
    __shared__ float red[4];
    if ((tid & 63) == 0) red[tid >> 6] = am;
    __syncthreads();
    am = fmaxf(fmaxf(red[0], red[1]), fmaxf(red[2], red[3]));
    am = fmaxf(am, 1e-30f);
    if (tid == 0) sx[row] = am / 127.f;
    const float inv = 127.f / am;
    int* outw = reinterpret_cast<int*>(xq + (size_t)row * Kdim);
    #pragma unroll
    for (int j = 0; j < 4; ++j) {
        const int q0 = (int)rintf(v[j].x * inv) & 255;
        const int q1 = (int)rintf(v[j].y * inv) & 255;
        const int q2 = (int)rintf(v[j].z * inv) & 255;
        const int q3 = (int)rintf(v[j].w * inv) & 255;
        outw[tid + 256 * j] = q0 | (q1 << 8) | (q2 << 16) | (q3 << 24);
    }
}

// pack W int32 (values in [-128,127]) -> int8
__global__ __launch_bounds__(256)
void pack_w_int8(const int* __restrict__ w, char* __restrict__ wq, int n4) {
    int idx = blockIdx.x * blockDim.x + threadIdx.x;
    const int stride = gridDim.x * blockDim.x;
    int* out = reinterpret_cast<int*>(wq);
    for (int i = idx; i < n4; i += stride) {
        const int4 a = reinterpret_cast<const int4*>(w)[i];
        out[i] = (a.x & 255) | ((a.y & 255) << 8) |
                 ((a.z & 255) << 16) | ((a.w & 255) << 24);
    }
}

// ---------------- 256x256 2-barrier/K-tile int8 GEMM ------------------------

__global__ __launch_bounds__(512, 2)
void gemm_i8_flat(const char* __restrict__ A,   // [M][K] int8
                  const char* __restrict__ B,   // [N][K] int8
                  const float* __restrict__ scale,
                  const float* __restrict__ bias,
                  const float* __restrict__ sx,
                  float* __restrict__ Out)
{
    // [buf][half: A0,A1,B0,B1][16 KiB] = 128 KiB
    __shared__ __align__(16) char smem[2][4][16384];

    const int tid = threadIdx.x;
    int bid = blockIdx.x;
    bid = (bid & 7) * 64 + (bid >> 3);          // bijective XCD swizzle (512%8==0)
    const int tn = bid & 15;                    // N/BN = 16
    const int tm = bid >> 4;                    // M/BM = 32
    const int brow = tm * BM;
    const int bcol = tn * BN;

    const int lane = tid & 63;
    const int w    = tid >> 6;                  // 8 waves
    const int wr   = w >> 2;                    // 2 M-waves
    const int wc   = w & 3;                     // 4 N-waves
    const int r32  = lane & 31;
    const int h    = lane >> 5;                 // k-group
    const size_t K1 = (size_t)Kdim;             // row stride in bytes (int8)

    // staging source (pre-swizzled global address; LDS dest stays linear)
    // two-level swizzle nibble = (l&7) ^ (row&7) ^ ((row>>3)&3)
    const int swzb = ((lane & 7) ^ (lane >> 3) ^ (w & 3)) << 4;
    const char* aStageSrc = A + (size_t)(brow + w * 8 + (lane >> 3)) * K1 + swzb;
    const char* bStageSrc = B + (size_t)(bcol + w * 8 + (lane >> 3)) * K1 + swzb;

    auto stageA = [&](int bufb, int hh, int tt) {   // 2 gloads
        const char* s = aStageSrc + (size_t)(hh * 128) * K1 + (size_t)tt * BKB;
        char* d = &smem[bufb][hh][w * 1024];
        gload_lds16(s, d);
        gload_lds16(s + 64 * K1, d + 8192);
    };
    auto stageB = [&](int bufb, int hh, int tt) {
        const char* s = bStageSrc + (size_t)(hh * 128) * K1 + (size_t)tt * BKB;
        char* d = &smem[bufb][2 + hh][w * 1024];
        gload_lds16(s, d);
        gload_lds16(s + 64 * K1, d + 8192);
    };

    // ds_read bases (128B rows; geometry identical to rounds 6/7)
    const char* aBase[2] = { &smem[0][wr][0] + r32 * 128,
                             &smem[1][wr][0] + r32 * 128 };
    const char* bBase[2] = { &smem[0][2 + (wc >> 1)][0] + ((wc & 1) * 64 + r32) * 128,
                             &smem[1][2 + (wc >> 1)][0] + ((wc & 1) * 64 + r32) * 128 };
    const int frx = ((r32 & 7) ^ (r32 >> 3)) << 4;
    int colb[4];
    #pragma unroll
    for (int ks = 0; ks < 4; ++ks) colb[ks] = (ks * 32 + h * 16) ^ frx;

    int32x16 acc[4][2] = {};     // [m-tile][n-tile]
    int32x4 af[2][4], bf[2][4];  // af reused across the two m-pairs

    auto ldA = [&](const char* base, int MH) {
        #pragma unroll
        for (int mt = 0; mt < 2; ++mt) {
            const char* p = base + ((MH) * 2 + mt) * 4096;   // 32 rows * 128B
            #pragma unroll
            for (int ks = 0; ks < 4; ++ks)
                af[mt][ks] = *reinterpret_cast<const int32x4*>(p + colb[ks]);
        }
    };
    auto ldB = [&](const char* base) {
        #pragma unroll
        for (int nt = 0; nt < 2; ++nt) {
            const char* p = base + nt * 4096;
            #pragma unroll
            for (int ks = 0; ks < 4; ++ks)
                bf[nt][ks] = *reinterpret_cast<const int32x4*>(p + colb[ks]);
        }
    };

    // ---- prologue: buf0 full (t0) + buf1.B (t1); leave buf1.B in flight
    stageA(0, 0, 0); stageA(0, 1, 0);
    stageB(0, 0, 0); stageB(0, 1, 0);
    stageB(1, 0, 1); stageB(1, 1, 1);
    WAITV4();          // buf0's 8 loads landed; buf1.B may remain
    BARRIER();

    // ---- main loop: 15 iterations of 2 segments ----
    for (int i = 0; i < KT / 2 - 1; ++i) {
        const int t = 2 * i;

        // segment t (buf0); stage A(buf1<-t+1), B(buf0<-t+2)
        ldB(bBase[0]); ldA(aBase[0], 0);
        BARRIER();
        CLUSTER(0);
        ldA(aBase[0], 1);
        stageA(1, 0, t + 1); stageA(1, 1, t + 1);
        stageB(0, 0, t + 2); stageB(0, 1, t + 2);
        CLUSTER(2);
        WAITV4();
        BARRIER();

        // segment t+1 (buf1); stage A(buf0<-t+2), B(buf1<-t+3)
        ldB(bBase[1]); ldA(aBase[1], 0);
        BARRIER();
        CLUSTER(0);
        ldA(aBase[1], 1);
        stageA(0, 0, t + 2); stageA(0, 1, t + 2);
        stageB(1, 0, t + 3); stageB(1, 1, t + 3);
        CLUSTER(2);
        WAITV4();
        BARRIER();
    }

    // ---- tail segment KT-2 (buf0): stage only A(buf1<-KT-1); drain
    {
        ldB(bBase[0]); ldA(aBase[0], 0);
        BARRIER();
        CLUSTER(0);
        ldA(aBase[0], 1);
        stageA(1, 0, KT - 1); stageA(1, 1, KT - 1);
        CLUSTER(2);
        WAITV0();          // buf1(KT-1) fully landed
        BARRIER();
    }
    // ---- tail segment KT-1 (buf1): no stages, no wait
    {
        ldB(bBase[1]); ldA(aBase[1], 0);
        BARRIER();
        CLUSTER(0);
        ldA(aBase[1], 1);
        CLUSTER(2);
    }

    // epilogue: out = acc * scale[col] * scale_x[row] + bias[col]
    // C/D (32x32): col=lane&31, row=(reg&3)+8*(reg>>2)+4*(lane>>5)
    #pragma unroll
    for (int nt = 0; nt < 2; ++nt) {
        const int col = bcol + wc * 64 + nt * 32 + r32;
        const float sc = scale[col];
        const float bi = bias[col];
        #pragma unroll
        for (int mt = 0; mt < 4; ++mt) {
            const int rb = brow + wr * 128 + mt * 32 + 4 * h;
            #pragma unroll
            for (int q = 0; q < 4; ++q) {
                const int r4 = rb + 8 * q;
                #pragma unroll
                for (int r = 0; r < 4; ++r) {
                    const float sxr = sx[r4 + r];
                    Out[(size_t)(r4 + r) * Ndim + col] =
                        (float)acc[mt][nt][q * 4 + r] * (sc * sxr) + bi;
                }
            }
        }
    }
}

// ---------------- fallback (round-1 kernel) if ws too small -----------------

__device__ __forceinline__ int swz_fb(int row, int colbyte) {
    return row * 128 + (colbyte ^ ((row & 7) << 4));
}

__global__ __launch_bounds__(256)
void compressed_linear_fb(const float* __restrict__ X,
                          const int*   __restrict__ W,
                          const float* __restrict__ scale,
                          const float* __restrict__ bias,
                          float* __restrict__ Out)
{
    __shared__ __align__(16) ushort_t lA[128 * 64];
    __shared__ __align__(16) ushort_t lB[128 * 64];
    const int tid = threadIdx.x;
    const int bid = blockIdx.x;
    const int tn = bid & 31, tm = bid >> 5;
    const int brow = tm * 128, bcol = tn * 128;
    const int r0 = tid >> 3, c0 = tid & 7;
    float4 aPre[4][2]; int4 bPre[4][2];
    const int lane = tid & 63, w = tid >> 6;
    const int wr = w >> 1, wc = w & 1, fr = lane & 15, fq = lane >> 4;
    f32x4 acc[4][4] = {};

    auto loadTiles = [&](int t) {
        const int k0 = t * 64;
        #pragma unroll
        for (int i = 0; i < 4; i++) {
            const int row = r0 + 32 * i;
            const float4* pa = reinterpret_cast<const float4*>(X + (size_t)(brow + row) * Kdim + k0 + c0 * 8);
            aPre[i][0] = pa[0]; aPre[i][1] = pa[1];
            const int4* pb = reinterpret_cast<const int4*>(W + (size_t)(bcol + row) * Kdim + k0 + c0 * 8);
            bPre[i][0] = pb[0]; bPre[i][1] = pb[1];
        }
    };
    auto writeLDS = [&]() {
        #pragma unroll
        for (int i = 0; i < 4; i++) {
            const int row = r0 + 32 * i;
            const int off = swz_fb(row, c0 * 16);
            short8 va, vb;
            va[0] = (short)f2bf(aPre[i][0].x); va[1] = (short)f2bf(aPre[i][0].y);
            va[2] = (short)f2bf(aPre[i][0].z); va[3] = (short)f2bf(aPre[i][0].w);
            va[4] = (short)f2bf(aPre[i][1].x); va[5] = (short)f2bf(aPre[i][1].y);
            va[6] = (short)f2bf(aPre[i][1].z); va[7] = (short)f2bf(aPre[i][1].w);
            vb[0] = (short)f2bf((float)bPre[i][0].x); vb[1] = (short)f2bf((float)bPre[i][0].y);
            vb[2] = (short)f2bf((float)bPre[i][0].z); vb[3] = (short)f2bf((float)bPre[i][0].w);
            vb[4] = (short)f2bf((float)bPre[i][1].x); vb[5] = (short)f2bf((float)bPre[i][1].y);
            vb[6] = (short)f2bf((float)bPre[i][1].z); vb[7] = (short)f2bf((float)bPre[i][1].w);
            *reinterpret_cast<short8*>(reinterpret_cast<char*>(lA) + off) = va;
            *reinterpret_cast<short8*>(reinterpret_cast<char*>(lB) + off) = vb;
        }
    };

    loadTiles(0);
    for (int t = 0; t < Kdim / 64; t++) {
        writeLDS();
        __syncthreads();
        if (t + 1 < Kdim / 64) loadTiles(t + 1);
        #pragma unroll
        for (int kk = 0; kk < 2; kk++) {
            short8 afv[4], bfv[4];
            const int cb = kk * 64 + fq * 16;
            #pragma unroll
            for (int m = 0; m < 4; m++) {
                const int row = wr * 64 + m * 16 + fr;
                afv[m] = *reinterpret_cast<const short8*>(reinterpret_cast<const char*>(lA) + swz_fb(row, cb));
            }
            #pragma unroll
            for (int n = 0; n < 4; n++) {
                const int row = wc * 64 + n * 16 + fr;
                bfv[n] = *reinterpret_cast<const short8*>(reinterpret_cast<const char*>(lB) + swz_fb(row, cb));
            }
            #pragma unroll
            for (int m = 0; m < 4; m++)
                #pragma unroll
                for (int n = 0; n < 4; n++)
                    acc[m][n] = __builtin_amdgcn_mfma_f32_16x16x32_bf16(afv[m], bfv[n], acc[m][n], 0, 0, 0);
        }
        __syncthreads();
    }
    #pragma unroll
    for (int n = 0; n < 4; n++) {
        const int col = bcol + wc * 64 + n * 16 + fr;
        const float sc = scale[col];
        const float bi = bias[col];
        #pragma unroll
        for (int m = 0; m < 4; m++) {
            const int rbase = brow + wr * 64 + m * 16 + fq * 4;
            #pragma unroll
            for (int j = 0; j < 4; j++)
                Out[(size_t)(rbase + j) * Ndim + col] = acc[m][n][j] * sc + bi;
        }
    }
}

// ---------------------------------------------------------------------------

extern "C" void kernel_launch(void* const* d_in, const int* in_sizes, int n_in,
                              void* d_out, int out_size, void* d_ws, size_t ws_size,
                              hipStream_t stream) {
    const float* x     = (const float*)d_in[0];
    const int*   w8    = (const int*)d_in[1];
    const float* scale = (const float*)d_in[2];
    const float* bias  = (const float*)d_in[3];
    float* out = (float*)d_out;

    const size_t xq_bytes = (size_t)Mdim * Kdim;        // 32 MiB
    const size_t wq_bytes = (size_t)Ndim * Kdim;        // 16 MiB
    const size_t sx_bytes = (size_t)Mdim * sizeof(float);

    if (ws_size >= xq_bytes + wq_bytes + sx_bytes) {
        char*  xq = (char*)d_ws;
        char*  wq = (char*)d_ws + xq_bytes;
        float* sx = (float*)((char*)d_ws + xq_bytes + wq_bytes);
        quant_x_rowwise<<<Mdim, 256, 0, stream>>>(x, xq, sx);
        pack_w_int8<<<2048, 256, 0, stream>>>(w8, wq, (Ndim * Kdim) / 4);
        dim3 grid((Mdim / BM) * (Ndim / BN));           // 32*16 = 512 blocks
        gemm_i8_flat<<<grid, dim3(512), 0, stream>>>(xq, wq, scale, bias, sx, out);
    } else {
        dim3 grid((Mdim / 128) * (Ndim / 128));         // 2048 blocks
        compressed_linear_fb<<<grid, dim3(256), 0, stream>>>(x, w8, scale, bias, out);
    }
}